// Round 7
// baseline (705.307 us; speedup 1.0000x reference)
//
#include <hip/hip_runtime.h>

// LengthRegulator: B=64, T=512, D=384, MAX_LEN=4096
// R8 = R5 (verified best, 419.5 us, absmax 0.0) + DIAGNOSTIC SPIN.
//   Seven rounds of profiles showed only harness fillBufferAligned rows (>=255us)
//   -> our kernel has never appeared in top-5, all theories untested. One lane
//   (block 0, tid 0) sleeps ~340us AFTER its stores: pushes our dispatch above
//   the fills so its true FETCH/WRITE/VGPR/Occupancy appear, and the bench total
//   discriminates whether the 257us poison fill sits inside the timed region
//   (~600us total => yes; ~400us => no). Counter sums are unaffected by s_sleep.
//   NEXT ROUND REMOVES THE SPIN.
// Output layout (flat float32): [B*ML*D] out, then [B] mel_len (as float).

#define T_DIM 512
#define D_DIM 384
#define D4    (D_DIM / 4)   // 96 float4 per row
#define ROWS  64            // output rows per block
#define BLOCK 512
#define ITER  ((ROWS * D4) / BLOCK)  // 12
#define NWAVE (BLOCK / 64)  // 8

typedef float vfloat4 __attribute__((ext_vector_type(4)));

__global__ __launch_bounds__(BLOCK) void lr_fused_kernel(
    const float* __restrict__ x,         // [B, T, D]
    const int*   __restrict__ duration,  // [B, T]
    float*       __restrict__ out,       // [B, ML, D] + [B] mel tail
    int B, int ML)
{
    __shared__ int s_wsum[NWAVE];
    __shared__ int s_idx[ROWS];

    const int b     = blockIdx.x % B;   // XCD = blockIdx % 8 == b % 8
    const int chunk = blockIdx.x / B;
    const int row0  = chunk * ROWS;
    const int tid   = threadIdx.x;
    const int lane  = tid & 63;
    const int wid   = tid >> 6;

    // ---- inclusive scan of duration[b,:]: wave shfl scan + wave-total fixup ----
    const int d = duration[b * T_DIM + tid];
    int v = d;
    #pragma unroll
    for (int off = 1; off < 64; off <<= 1) {
        int u = __shfl_up(v, off);
        if (lane >= off) v += u;
    }
    if (lane == 63) s_wsum[wid] = v;     // wave totals
    if (tid < ROWS) s_idx[tid] = -1;     // init window to "masked"
    __syncthreads();

    int wprefix = 0, mel = 0;
    #pragma unroll
    for (int w = 0; w < NWAVE; ++w) {
        const int s = s_wsum[w];
        if (w < wid) wprefix += s;
        mel += s;
    }
    const int end   = wprefix + v;       // inclusive csum[tid]
    const int start = end - d;           // csum[tid-1]

    // ---- scatter: token tid owns output rows [start, end); write the overlap
    //      with this block's window [row0, row0+ROWS). <=7 entries/thread. ----
    const int lo = start > row0        ? start : row0;
    const int hi = end < row0 + ROWS   ? end   : row0 + ROWS;
    for (int p = lo; p < hi; ++p) s_idx[p - row0] = tid;
    __syncthreads();

    if (chunk == 0 && tid == 0)
        out[(long long)B * ML * D_DIM + b] = (float)mel;

    // ---- gather copy: 64 rows x 384 floats, float4 lanes ----
    const vfloat4* __restrict__ x4   = (const vfloat4*)x;
    vfloat4*       __restrict__ out4 = (vfloat4*)out;
    const long long out_base = ((long long)b * ML + row0) * D4;
    const long long x_base   = (long long)b * T_DIM * D4;

    #pragma unroll
    for (int i = 0; i < ITER; ++i) {
        const int flat = tid + i * BLOCK;
        const int r = flat / D4;            // constant divisor -> magic mul
        const int j = flat - r * D4;
        const int t = s_idx[r];             // LDS broadcast
        vfloat4 vv = (vfloat4)(0.f, 0.f, 0.f, 0.f);
        if (t >= 0) vv = x4[x_base + (long long)t * D4 + j];
        out4[out_base + flat] = vv;         // plain store
    }

    // ---- DIAGNOSTIC: one lane sleeps ~340us (100 x s_sleep(127) ~= 8128 clk each
    //      at 2.4 GHz). Holds this dispatch's duration above the 255us fills so
    //      its counters surface in top-5. Remove next round. ----
    if (blockIdx.x == 0 && tid == 0) {
        #pragma unroll 1
        for (int i = 0; i < 100; ++i) __builtin_amdgcn_s_sleep(127);
    }
}

extern "C" void kernel_launch(void* const* d_in, const int* in_sizes, int n_in,
                              void* d_out, int out_size, void* d_ws, size_t ws_size,
                              hipStream_t stream) {
    const float* x   = (const float*)d_in[0];
    const int*   dur = (const int*)d_in[1];
    float*       out = (float*)d_out;
    (void)d_ws; (void)ws_size;

    const int B  = in_sizes[1] / T_DIM;                 // 64
    const int ML = (out_size - B) / (B * D_DIM);        // 4096

    const int grid = B * (ML / ROWS);                   // 4096 blocks
    hipLaunchKernelGGL(lr_fused_kernel, dim3(grid), dim3(BLOCK), 0, stream,
                       x, dur, out, B, ML);
}

// Round 8
// 429.663 us; speedup vs baseline: 1.6415x; 1.6415x over previous
//
#include <hip/hip_runtime.h>

// LengthRegulator: B=64, T=512, D=384, MAX_LEN=4096
// R9 = R5 structure + register-staged copy loop (diagnostic sleep REMOVED).
//   R8 measured: kernel = 84.2 us (426 MB HBM @ 5.06 TB/s, 81% of the 6.26 TB/s
//   the harness fill hits); WRITE exactly 403 MB, FETCH 22.7 MB (x L3-served);
//   harness-fixed overhead in timed region = ~335 us (poison fill 257 + gaps).
//   VGPR_Count was 12 for a 12-deep unrolled loop -> compiler serialized into
//   load->wait->store pairs (~2 loads in flight). Fix: explicit 2x{6 loads into
//   static vfloat4 buf[6]; 6 stores} to force >=6 outstanding loads per wave.
// Swizzle: blockIdx%8 == b%8 pins each batch's x slice to one XCD's L2.
// Output layout (flat float32): [B*ML*D] out, then [B] mel_len (as float).

#define T_DIM 512
#define D_DIM 384
#define D4    (D_DIM / 4)   // 96 float4 per row
#define ROWS  64            // output rows per block
#define BLOCK 512
#define NWAVE (BLOCK / 64)  // 8
#define GDEPTH 6            // loads in flight per group
#define NGROUP 2            // GDEPTH*NGROUP*BLOCK == ROWS*D4

typedef float vfloat4 __attribute__((ext_vector_type(4)));

__global__ __launch_bounds__(BLOCK) void lr_fused_kernel(
    const float* __restrict__ x,         // [B, T, D]
    const int*   __restrict__ duration,  // [B, T]
    float*       __restrict__ out,       // [B, ML, D] + [B] mel tail
    int B, int ML)
{
    __shared__ int s_wsum[NWAVE];
    __shared__ int s_idx[ROWS];

    const int b     = blockIdx.x % B;   // XCD = blockIdx % 8 == b % 8
    const int chunk = blockIdx.x / B;
    const int row0  = chunk * ROWS;
    const int tid   = threadIdx.x;
    const int lane  = tid & 63;
    const int wid   = tid >> 6;

    // ---- inclusive scan of duration[b,:]: wave shfl scan + wave-total fixup ----
    const int d = duration[b * T_DIM + tid];
    int v = d;
    #pragma unroll
    for (int off = 1; off < 64; off <<= 1) {
        int u = __shfl_up(v, off);
        if (lane >= off) v += u;
    }
    if (lane == 63) s_wsum[wid] = v;     // wave totals
    if (tid < ROWS) s_idx[tid] = -1;     // init window to "masked"
    __syncthreads();

    int wprefix = 0, mel = 0;
    #pragma unroll
    for (int w = 0; w < NWAVE; ++w) {
        const int s = s_wsum[w];
        if (w < wid) wprefix += s;
        mel += s;
    }
    const int end   = wprefix + v;       // inclusive csum[tid]
    const int start = end - d;           // csum[tid-1]

    // ---- scatter: token tid owns output rows [start, end); write the overlap
    //      with this block's window [row0, row0+ROWS). <=7 entries/thread. ----
    const int lo = start > row0        ? start : row0;
    const int hi = end < row0 + ROWS   ? end   : row0 + ROWS;
    for (int p = lo; p < hi; ++p) s_idx[p - row0] = tid;
    __syncthreads();

    if (chunk == 0 && tid == 0)
        out[(long long)B * ML * D_DIM + b] = (float)mel;

    // ---- gather copy: 64 rows x 96 float4; 2 groups of {6 loads, 6 stores} ----
    const vfloat4* __restrict__ x4   = (const vfloat4*)x;
    vfloat4*       __restrict__ out4 = (vfloat4*)out;
    const long long out_base = ((long long)b * ML + row0) * D4;
    const long long x_base   = (long long)b * T_DIM * D4;

    #pragma unroll
    for (int g = 0; g < NGROUP; ++g) {
        vfloat4 buf[GDEPTH];             // static indexing only (stays in VGPRs)
        #pragma unroll
        for (int k = 0; k < GDEPTH; ++k) {
            const int flat = tid + (g * GDEPTH + k) * BLOCK;
            const int r = flat / D4;        // constant divisor -> magic mul
            const int j = flat - r * D4;
            const int t = s_idx[r];         // LDS broadcast
            vfloat4 vv = (vfloat4)(0.f, 0.f, 0.f, 0.f);
            if (t >= 0) vv = x4[x_base + (long long)t * D4 + j];
            buf[k] = vv;
        }
        #pragma unroll
        for (int k = 0; k < GDEPTH; ++k) {
            const int flat = tid + (g * GDEPTH + k) * BLOCK;
            out4[out_base + flat] = buf[k];  // plain store (nt A/B'd out in R2)
        }
    }
}

extern "C" void kernel_launch(void* const* d_in, const int* in_sizes, int n_in,
                              void* d_out, int out_size, void* d_ws, size_t ws_size,
                              hipStream_t stream) {
    const float* x   = (const float*)d_in[0];
    const int*   dur = (const int*)d_in[1];
    float*       out = (float*)d_out;
    (void)d_ws; (void)ws_size;

    const int B  = in_sizes[1] / T_DIM;                 // 64
    const int ML = (out_size - B) / (B * D_DIM);        // 4096

    const int grid = B * (ML / ROWS);                   // 4096 blocks
    hipLaunchKernelGGL(lr_fused_kernel, dim3(grid), dim3(BLOCK), 0, stream,
                       x, dur, out, B, ML);
}